// Round 2
// baseline (642.008 us; speedup 1.0000x reference)
//
#include <hip/hip_runtime.h>

#define CH 128   // in/hidden channels

// ---------------- K1: init deg=1.0 (self-loop weight), cnt=0 -----------------
__global__ __launch_bounds__(256) void k_init(float* __restrict__ deg,
                                              int* __restrict__ cnt, int n) {
    int i = blockIdx.x * 256 + threadIdx.x;
    if (i < n) { deg[i] = 1.0f; cnt[i] = 0; }
}

// ---------------- K2: deg[col[e]] += w[e];  cnt[col[e]] += 1 -----------------
__global__ __launch_bounds__(256) void k_deg(const int* __restrict__ col,
                                             const float* __restrict__ w,
                                             float* __restrict__ deg,
                                             int* __restrict__ cnt, int e_cnt) {
    int e = blockIdx.x * 256 + threadIdx.x;
    if (e < e_cnt) {
        int c = col[e];
        atomicAdd(&deg[c], w[e]);
        atomicAdd(&cnt[c], 1);
    }
}

// ---------------- K3: deg -> dinv = rsqrt(deg) in place ----------------------
__global__ __launch_bounds__(256) void k_dinv(float* __restrict__ deg, int n) {
    int i = blockIdx.x * 256 + threadIdx.x;
    if (i < n) deg[i] = rsqrtf(deg[i]);
}

// ---------------- Scan pass A: per-block (1024-chunk) sums -------------------
__global__ __launch_bounds__(256) void k_scanA(const int* __restrict__ cnt,
                                               int* __restrict__ part, int n) {
    int b = blockIdx.x, t = threadIdx.x;
    int base = b * 1024 + t * 4;
    int sum = 0;
#pragma unroll
    for (int k = 0; k < 4; ++k) {
        int idx = base + k;
        if (idx < n) sum += cnt[idx];
    }
#pragma unroll
    for (int m = 32; m; m >>= 1) sum += __shfl_xor(sum, m);
    __shared__ int ws[4];
    if ((t & 63) == 0) ws[t >> 6] = sum;
    __syncthreads();
    if (t == 0) part[b] = ws[0] + ws[1] + ws[2] + ws[3];
}

// ---------------- Scan pass B: exclusive scan of block partials (1 wave) -----
__global__ __launch_bounds__(64) void k_scanB(int* __restrict__ part, int nb) {
    int lane = threadIdx.x & 63;
    int run = 0;
    for (int base = 0; base < nb; base += 64) {
        int idx = base + lane;
        int v = (idx < nb) ? part[idx] : 0;
        int incl = v;
#pragma unroll
        for (int d = 1; d < 64; d <<= 1) {
            int u = __shfl_up(incl, d);
            if (lane >= d) incl += u;
        }
        int tot = __shfl(incl, 63);
        if (idx < nb) part[idx] = run + incl - v;
        run += tot;
    }
}

// ---------------- Scan pass C: rowptr (exclusive) + cursor copy --------------
__global__ __launch_bounds__(256) void k_scanC(const int* __restrict__ cnt,
                                               const int* __restrict__ part,
                                               int* __restrict__ rowptr,
                                               int* __restrict__ cursor, int n) {
    int b = blockIdx.x, t = threadIdx.x;
    int lane = t & 63, wv = t >> 6;
    int base = b * 1024 + t * 4;
    int v[4];
    int sum = 0;
#pragma unroll
    for (int k = 0; k < 4; ++k) {
        int idx = base + k;
        v[k] = (idx < n) ? cnt[idx] : 0;
        sum += v[k];
    }
    int incl = sum;
#pragma unroll
    for (int d = 1; d < 64; d <<= 1) {
        int u = __shfl_up(incl, d);
        if (lane >= d) incl += u;
    }
    __shared__ int wsum[4];
    if (lane == 63) wsum[wv] = incl;
    __syncthreads();
    int woff = 0;
    for (int i = 0; i < wv; ++i) woff += wsum[i];
    int excl = part[b] + woff + incl - sum;
#pragma unroll
    for (int k = 0; k < 4; ++k) {
        int idx = base + k;
        if (idx < n) {
            rowptr[idx] = excl;
            cursor[idx] = excl;
            excl += v[k];
            if (idx == n - 1) rowptr[n] = excl;
        }
    }
}

// ---------------- Permute: edges -> dst-sorted (src, norm) pairs -------------
__global__ __launch_bounds__(256) void k_permute(const int* __restrict__ row,
                                                 const int* __restrict__ col,
                                                 const float* __restrict__ w,
                                                 const float* __restrict__ dinv,
                                                 int* __restrict__ cursor,
                                                 int* __restrict__ src_sorted,
                                                 float* __restrict__ nrm_sorted,
                                                 int e_cnt) {
    int e = blockIdx.x * 256 + threadIdx.x;
    if (e < e_cnt) {
        int r = row[e], c = col[e];
        int pos = atomicAdd(&cursor[c], 1);
        src_sorted[pos] = r;
        nrm_sorted[pos] = dinv[r] * w[e] * dinv[c];
    }
}

// ---------------- GEMM: xW = x @ W1 (fp32, W columns in VGPRs) ---------------
#define GEMM_ROWS 16
__global__ __launch_bounds__(256) void k_gemm(const float* __restrict__ x,
                                              const float* __restrict__ W,
                                              float* __restrict__ xW,
                                              int nrows, int nchunks) {
    __shared__ float xs[GEMM_ROWS * CH];
    const int tid    = threadIdx.x;
    const int wave   = tid >> 6;
    const int lane   = tid & 63;
    const int c      = ((wave & 1) << 6) | lane;  // column this lane owns
    const int stream = wave >> 1;                 // 0 or 1

    float wc[CH];
#pragma unroll
    for (int k = 0; k < CH; ++k) wc[k] = W[k * CH + c];

    for (int chunk = blockIdx.x; chunk < nchunks; chunk += gridDim.x) {
        const int row0 = chunk * GEMM_ROWS;
        __syncthreads();  // previous-iter readers done
        {
            const float4* src = (const float4*)(x + (size_t)row0 * CH);
            float4* dst = (float4*)xs;
#pragma unroll
            for (int i = tid; i < GEMM_ROWS * (CH / 4); i += 256) {
                int r = i >> 5;
                if (row0 + r < nrows) dst[i] = src[i];
            }
        }
        __syncthreads();
        for (int r = stream; r < GEMM_ROWS; r += 2) {
            if (row0 + r >= nrows) break;
            const float* xr = xs + r * CH;
            float acc = 0.f;
#pragma unroll
            for (int k = 0; k < CH; ++k) acc += xr[k] * wc[k];
            xW[(size_t)(row0 + r) * CH + c] = acc;
        }
    }
}

// ---------------- Gather1: s[d] = (agg(d) + dinv^2 xW[d] + b1) . W2 ----------
// one wave per destination node; 2 channels per lane
__global__ __launch_bounds__(256) void k_gather1(const float* __restrict__ xW,
                                                 const int* __restrict__ rowptr,
                                                 const int* __restrict__ src_sorted,
                                                 const float* __restrict__ nrm_sorted,
                                                 const float* __restrict__ dinv,
                                                 const float* __restrict__ b1,
                                                 const float* __restrict__ W2,
                                                 float* __restrict__ s, int n) {
    int wid  = blockIdx.x * 4 + (threadIdx.x >> 6);
    if (wid >= n) return;
    int lane = threadIdx.x & 63;
    float acc0 = 0.f, acc1 = 0.f;
    int jb = rowptr[wid], je = rowptr[wid + 1];
    for (int j = jb; j < je; ++j) {
        int srcn  = src_sorted[j];
        float nrm = nrm_sorted[j];
        const float* xr = xW + (size_t)srcn * CH;
        acc0 += nrm * xr[lane];
        acc1 += nrm * xr[64 + lane];
    }
    float di = dinv[wid];
    float d2 = di * di;
    const float* xd = xW + (size_t)wid * CH;
    float v0 = acc0 + d2 * xd[lane]      + b1[lane];
    float v1 = acc1 + d2 * xd[64 + lane] + b1[64 + lane];
    float dot = v0 * W2[lane] + v1 * W2[64 + lane];
#pragma unroll
    for (int m = 32; m; m >>= 1) dot += __shfl_xor(dot, m);
    if (lane == 0) s[wid] = dot;
}

// ---------------- Gather2: out[d] = b2 + dinv^2 s[d] + sum nrm*s[src] --------
__global__ __launch_bounds__(256) void k_gather2(const int* __restrict__ rowptr,
                                                 const int* __restrict__ src_sorted,
                                                 const float* __restrict__ nrm_sorted,
                                                 const float* __restrict__ dinv,
                                                 const float* __restrict__ s,
                                                 const float* __restrict__ b2,
                                                 float* __restrict__ out, int n) {
    int i = blockIdx.x * 256 + threadIdx.x;
    if (i >= n) return;
    float di = dinv[i];
    float acc = b2[0] + di * di * s[i];
    int je = rowptr[i + 1];
    for (int j = rowptr[i]; j < je; ++j)
        acc += nrm_sorted[j] * s[src_sorted[j]];
    out[i] = acc;
}

extern "C" void kernel_launch(void* const* d_in, const int* in_sizes, int n_in,
                              void* d_out, int out_size, void* d_ws, size_t ws_size,
                              hipStream_t stream) {
    const float* x   = (const float*)d_in[0];
    const int*   ei  = (const int*)d_in[1];
    const float* w   = (const float*)d_in[2];
    const float* W1  = (const float*)d_in[3];
    const float* b1  = (const float*)d_in[4];
    const float* W2  = (const float*)d_in[5];
    const float* b2  = (const float*)d_in[6];
    float* out = (float*)d_out;

    const int n     = in_sizes[0] / CH;   // 100000
    const int e_cnt = in_sizes[2];        // 1600000
    const int* row = ei;
    const int* col = ei + e_cnt;

    // ---- workspace layout (all 4-byte types) ----
    float* ws         = (float*)d_ws;
    float* xW         = ws;                          // n*CH
    float* dinv       = xW + (size_t)n * CH;         // n (deg -> dinv in place)
    float* sArr       = dinv + n;                    // n
    float* nrm_sorted = sArr + n;                    // e_cnt
    int*   cnt        = (int*)(nrm_sorted + e_cnt);  // n
    int*   rowptr     = cnt + n;                     // n+1
    int*   cursor     = rowptr + n + 1;              // n
    int*   part       = cursor + n;                  // 1024
    int*   src_sorted = part + 1024;                 // e_cnt

    const int nb = (n + 1023) / 1024;                // scan blocks (98)

    k_init<<<(n + 255) / 256, 256, 0, stream>>>(dinv, cnt, n);
    k_deg<<<(e_cnt + 255) / 256, 256, 0, stream>>>(col, w, dinv, cnt, e_cnt);
    k_dinv<<<(n + 255) / 256, 256, 0, stream>>>(dinv, n);

    k_scanA<<<nb, 256, 0, stream>>>(cnt, part, n);
    k_scanB<<<1, 64, 0, stream>>>(part, nb);
    k_scanC<<<nb, 256, 0, stream>>>(cnt, part, rowptr, cursor, n);

    k_permute<<<(e_cnt + 255) / 256, 256, 0, stream>>>(row, col, w, dinv, cursor,
                                                       src_sorted, nrm_sorted, e_cnt);

    const int nchunks = (n + GEMM_ROWS - 1) / GEMM_ROWS;
    k_gemm<<<1024, 256, 0, stream>>>(x, W1, xW, n, nchunks);

    k_gather1<<<(n + 3) / 4, 256, 0, stream>>>(xW, rowptr, src_sorted, nrm_sorted,
                                               dinv, b1, W2, sArr, n);
    k_gather2<<<(n + 255) / 256, 256, 0, stream>>>(rowptr, src_sorted, nrm_sorted,
                                                   dinv, sArr, b2, out, n);
}

// Round 4
// 370.542 us; speedup vs baseline: 1.7326x; 1.7326x over previous
//
#include <hip/hip_runtime.h>

#define CH 128   // in/hidden channels

// ---- K0: u[r] = W1[r,:].W2 for r<128 ; u[128] = beta = b1.W2 ---------------
// one wave per row, float2 per lane, shuffle reduce
__global__ __launch_bounds__(256) void k_uw(const float* __restrict__ W1,
                                            const float* __restrict__ b1,
                                            const float* __restrict__ W2,
                                            float* __restrict__ u) {
    int wid  = blockIdx.x * 4 + (threadIdx.x >> 6);
    if (wid > CH) return;                 // rows 0..127 = W1, row 128 = b1
    int lane = threadIdx.x & 63;
    const float* rowp = (wid < CH) ? (W1 + (size_t)wid * CH) : b1;
    float2 xv = *(const float2*)(rowp + lane * 2);
    float2 vv = *(const float2*)(W2 + lane * 2);
    float acc = xv.x * vv.x + xv.y * vv.y;
#pragma unroll
    for (int m = 32; m; m >>= 1) acc += __shfl_xor(acc, m);
    if (lane == 0) u[wid] = acc;
}

// ---- K1: t[i] = x[i,:] . u  (N x 128 GEMV, memory-bound) -------------------
__global__ __launch_bounds__(256) void k_gemv(const float* __restrict__ X,
                                              const float* __restrict__ v,
                                              float* __restrict__ t, int n) {
    int wid  = blockIdx.x * 4 + (threadIdx.x >> 6);
    if (wid >= n) return;
    int lane = threadIdx.x & 63;
    float2 xv = *(const float2*)(X + (size_t)wid * CH + lane * 2);
    float2 vv = *(const float2*)(v + lane * 2);
    float acc = xv.x * vv.x + xv.y * vv.y;
#pragma unroll
    for (int m = 32; m; m >>= 1) acc += __shfl_xor(acc, m);
    if (lane == 0) t[wid] = acc;
}

// ---- K2: deg = 1.0 (self-loop weight) --------------------------------------
__global__ __launch_bounds__(256) void k_init(float* __restrict__ deg, int n) {
    int i = blockIdx.x * 256 + threadIdx.x;
    if (i < n) deg[i] = 1.0f;
}

// ---- K3: deg[col[e]] += w[e] ------------------------------------------------
__global__ __launch_bounds__(256) void k_deg(const int* __restrict__ col,
                                             const float* __restrict__ w,
                                             float* __restrict__ deg, int e_cnt) {
    int e = blockIdx.x * 256 + threadIdx.x;
    if (e < e_cnt) atomicAdd(&deg[col[e]], w[e]);
}

// ---- K4: dinv = rsqrt(deg) in place ; s1 = dinv^2 * t (self-loop term) -----
__global__ __launch_bounds__(256) void k_dinv_s1(float* __restrict__ deg,
                                                 const float* __restrict__ t,
                                                 float* __restrict__ s1, int n) {
    int i = blockIdx.x * 256 + threadIdx.x;
    if (i < n) {
        float di = rsqrtf(deg[i]);
        deg[i] = di;                       // deg buffer becomes dinv
        s1[i] = di * di * t[i];
    }
}

// ---- K5: s1[col] += dinv[row]*w*dinv[col] * t[row] -------------------------
__global__ __launch_bounds__(256) void k_scatter1(const int* __restrict__ row,
                                                  const int* __restrict__ col,
                                                  const float* __restrict__ w,
                                                  const float* __restrict__ dinv,
                                                  const float* __restrict__ t,
                                                  float* __restrict__ s1, int e_cnt) {
    int e = blockIdx.x * 256 + threadIdx.x;
    if (e >= e_cnt) return;
    int r = row[e], c = col[e];
    atomicAdd(&s1[c], dinv[r] * w[e] * dinv[c] * t[r]);
}

// ---- K6: out[i] = b2 + dinv^2 * (s1[i] + beta)  (self-loop + init) ---------
__global__ __launch_bounds__(256) void k_out_init(const float* __restrict__ dinv,
                                                  const float* __restrict__ s1,
                                                  const float* __restrict__ u,
                                                  const float* __restrict__ b2,
                                                  float* __restrict__ out, int n) {
    int i = blockIdx.x * 256 + threadIdx.x;
    if (i < n) {
        float di = dinv[i];
        out[i] = b2[0] + di * di * (s1[i] + u[CH]);
    }
}

// ---- K7: out[col] += dinv[row]*w*dinv[col] * (s1[row] + beta) --------------
__global__ __launch_bounds__(256) void k_scatter2(const int* __restrict__ row,
                                                  const int* __restrict__ col,
                                                  const float* __restrict__ w,
                                                  const float* __restrict__ dinv,
                                                  const float* __restrict__ s1,
                                                  const float* __restrict__ u,
                                                  float* __restrict__ out, int e_cnt) {
    int e = blockIdx.x * 256 + threadIdx.x;
    if (e >= e_cnt) return;
    int r = row[e], c = col[e];
    atomicAdd(&out[c], dinv[r] * w[e] * dinv[c] * (s1[r] + u[CH]));
}

extern "C" void kernel_launch(void* const* d_in, const int* in_sizes, int n_in,
                              void* d_out, int out_size, void* d_ws, size_t ws_size,
                              hipStream_t stream) {
    const float* x   = (const float*)d_in[0];
    const int*   ei  = (const int*)d_in[1];
    const float* w   = (const float*)d_in[2];
    const float* W1  = (const float*)d_in[3];
    const float* b1  = (const float*)d_in[4];
    const float* W2  = (const float*)d_in[5];
    const float* b2  = (const float*)d_in[6];
    float* out = (float*)d_out;

    const int n     = in_sizes[0] / CH;   // 100000
    const int e_cnt = in_sizes[2];        // 1600000
    const int* row = ei;
    const int* col = ei + e_cnt;

    // ---- workspace: u[132] | t[n] | deg/dinv[n] | s1[n]  (~1.2 MB) ----
    float* u    = (float*)d_ws;
    float* t    = u + 132;
    float* deg  = t + n;       // becomes dinv in place
    float* s1   = deg + n;

    k_uw<<<(CH + 1 + 3) / 4, 256, 0, stream>>>(W1, b1, W2, u);
    k_init<<<(n + 255) / 256, 256, 0, stream>>>(deg, n);
    k_gemv<<<(n + 3) / 4, 256, 0, stream>>>(x, u, t, n);
    k_deg<<<(e_cnt + 255) / 256, 256, 0, stream>>>(col, w, deg, e_cnt);
    k_dinv_s1<<<(n + 255) / 256, 256, 0, stream>>>(deg, t, s1, n);
    k_scatter1<<<(e_cnt + 255) / 256, 256, 0, stream>>>(row, col, w, deg, t, s1, e_cnt);
    k_out_init<<<(n + 255) / 256, 256, 0, stream>>>(deg, s1, u, b2, out, n);
    k_scatter2<<<(e_cnt + 255) / 256, 256, 0, stream>>>(row, col, w, deg, s1, u, out, e_cnt);
}

// Round 5
// 218.426 us; speedup vs baseline: 2.9393x; 1.6964x over previous
//
#include <hip/hip_runtime.h>

#define CH 128          // channels
#define CHUNK 2048      // edges per sort chunk
#define BSH 7           // 128 nodes per bucket
#define MAXBUCK 784     // >= NBUCK = ceil(100000/128) = 782

// ---- K0: u[r] = W1[r,:].W2 (r<128) ; u[128] = beta = b1.W2 -----------------
__global__ __launch_bounds__(256) void k_uw(const float* __restrict__ W1,
                                            const float* __restrict__ b1,
                                            const float* __restrict__ W2,
                                            float* __restrict__ u) {
    int wid  = blockIdx.x * 4 + (threadIdx.x >> 6);
    if (wid > CH) return;
    int lane = threadIdx.x & 63;
    const float* rowp = (wid < CH) ? (W1 + (size_t)wid * CH) : b1;
    float2 xv = *(const float2*)(rowp + lane * 2);
    float2 vv = *(const float2*)(W2 + lane * 2);
    float acc = xv.x * vv.x + xv.y * vv.y;
#pragma unroll
    for (int m = 32; m; m >>= 1) acc += __shfl_xor(acc, m);
    if (lane == 0) u[wid] = acc;
}

// ---- K1: t[i] = x[i,:].u  — float4, 2 rows per wave ------------------------
__global__ __launch_bounds__(256) void k_gemv(const float* __restrict__ X,
                                              const float* __restrict__ v,
                                              float* __restrict__ t, int n) {
    int wv   = blockIdx.x * 4 + (threadIdx.x >> 6);
    int lane = threadIdx.x & 63;
    int row  = wv * 2 + (lane >> 5);
    if (row >= n) return;
    float4 xv = *(const float4*)(X + (size_t)row * CH + (lane & 31) * 4);
    float4 vv = *(const float4*)(v + (lane & 31) * 4);
    float acc = xv.x * vv.x + xv.y * vv.y + xv.z * vv.z + xv.w * vv.w;
#pragma unroll
    for (int m = 16; m; m >>= 1) acc += __shfl_xor(acc, m);
    if ((lane & 31) == 0) t[row] = acc;
}

// ---- K2: per-chunk bucket histogram -> Ht[chunk][bucket] -------------------
__global__ __launch_bounds__(256) void k_hist(const int* __restrict__ col,
                                              int* __restrict__ Ht,
                                              int nbuck, int e_cnt) {
    __shared__ int h[MAXBUCK];
    int b = blockIdx.x, tid = threadIdx.x;
    for (int k = tid; k < nbuck; k += 256) h[k] = 0;
    __syncthreads();
    int e0 = b * CHUNK, e1 = min(e0 + CHUNK, e_cnt);
    for (int e = e0 + tid; e < e1; e += 256)
        atomicAdd(&h[col[e] >> BSH], 1);
    __syncthreads();
    int* rowp = Ht + (size_t)b * nbuck;
    for (int k = tid; k < nbuck; k += 256) rowp[k] = h[k];
}

// ---- K3: column-wise exclusive scan of Ht (wave per bucket) ----------------
__global__ __launch_bounds__(256) void k_colscan(int* __restrict__ Ht,
                                                 int* __restrict__ coltot,
                                                 int nchunk, int nbuck) {
    int j = blockIdx.x * 4 + (threadIdx.x >> 6);
    if (j >= nbuck) return;
    int lane = threadIdx.x & 63;
    int running = 0;
    for (int base = 0; base < nchunk; base += 64) {
        int idx = base + lane;
        int v = (idx < nchunk) ? Ht[(size_t)idx * nbuck + j] : 0;
        int incl = v;
#pragma unroll
        for (int d = 1; d < 64; d <<= 1) {
            int up = __shfl_up(incl, d);
            if (lane >= d) incl += up;
        }
        if (idx < nchunk) Ht[(size_t)idx * nbuck + j] = running + incl - v;
        running += __shfl(incl, 63);
    }
    if (lane == 0) coltot[j] = running;
}

// ---- K4: exclusive scan of column totals -> bucket_start -------------------
__global__ __launch_bounds__(64) void k_basescan(const int* __restrict__ coltot,
                                                 int* __restrict__ bstart, int nbuck) {
    int lane = threadIdx.x & 63;
    int running = 0;
    for (int base = 0; base < nbuck; base += 64) {
        int idx = base + lane;
        int v = (idx < nbuck) ? coltot[idx] : 0;
        int incl = v;
#pragma unroll
        for (int d = 1; d < 64; d <<= 1) {
            int up = __shfl_up(incl, d);
            if (lane >= d) incl += up;
        }
        if (idx < nbuck) bstart[idx] = running + incl - v;
        running += __shfl(incl, 63);
    }
    if (lane == 0) bstart[nbuck] = running;
}

// ---- K5: permute edges into bucket-sorted arrays (LDS cursors) -------------
__global__ __launch_bounds__(256) void k_permute(const int* __restrict__ row,
                                                 const int* __restrict__ col,
                                                 const float* __restrict__ w,
                                                 const int* __restrict__ Ht,
                                                 const int* __restrict__ bstart,
                                                 int* __restrict__ skey,
                                                 float* __restrict__ sw,
                                                 int nbuck, int e_cnt) {
    __shared__ int cur[MAXBUCK];
    int b = blockIdx.x, tid = threadIdx.x;
    const int* rowp = Ht + (size_t)b * nbuck;
    for (int k = tid; k < nbuck; k += 256) cur[k] = bstart[k] + rowp[k];
    __syncthreads();
    int e0 = b * CHUNK, e1 = min(e0 + CHUNK, e_cnt);
    for (int e = e0 + tid; e < e1; e += 256) {
        int r = row[e], c = col[e];
        float wv = w[e];
        int pos = atomicAdd(&cur[c >> BSH], 1);
        skey[pos] = r | ((c & 127) << 17);   // src (17b) | dstLocal (7b)
        sw[pos]   = wv;
    }
}

// ---- K6: deg agg (LDS) -> dinv, p = dinv*t ---------------------------------
__global__ __launch_bounds__(256) void k_dega(const int* __restrict__ skey,
                                              const float* __restrict__ sw,
                                              const int* __restrict__ bstart,
                                              const float* __restrict__ t,
                                              float* __restrict__ dinv,
                                              float* __restrict__ p, int n) {
    __shared__ float acc[128];
    int b = blockIdx.x, tid = threadIdx.x;
    if (tid < 128) acc[tid] = 1.0f;          // self-loop weight
    __syncthreads();
    int j1 = bstart[b + 1];
    for (int j = bstart[b] + tid; j < j1; j += 256)
        atomicAdd(&acc[skey[j] >> 17], sw[j]);
    __syncthreads();
    int node = (b << BSH) + tid;
    if (tid < 128 && node < n) {
        float di = rsqrtf(acc[tid]);
        dinv[node] = di;
        p[node] = di * t[node];
    }
}

// ---- K7: s1 agg (LDS) -> q = dinv*(s1+beta) --------------------------------
__global__ __launch_bounds__(256) void k_s1a(const int* __restrict__ skey,
                                             const float* __restrict__ sw,
                                             const int* __restrict__ bstart,
                                             const float* __restrict__ p,
                                             const float* __restrict__ dinv,
                                             const float* __restrict__ u,
                                             float* __restrict__ q, int n) {
    __shared__ float acc[128];
    int b = blockIdx.x, tid = threadIdx.x;
    if (tid < 128) acc[tid] = 0.f;
    __syncthreads();
    int j1 = bstart[b + 1];
    for (int j = bstart[b] + tid; j < j1; j += 256) {
        int key = skey[j];
        atomicAdd(&acc[key >> 17], sw[j] * p[key & 0x1FFFF]);
    }
    __syncthreads();
    int node = (b << BSH) + tid;
    if (tid < 128 && node < n) {
        float di = dinv[node];
        float s1 = di * (p[node] + acc[tid]);   // s1 = (A_hat t)[node]
        q[node] = di * (s1 + u[CH]);            // q = dinv*(s1+beta)
    }
}

// ---- K8: out agg (LDS): out = b2 + dinv*(q + sum w*q[src]) -----------------
__global__ __launch_bounds__(256) void k_outa(const int* __restrict__ skey,
                                              const float* __restrict__ sw,
                                              const int* __restrict__ bstart,
                                              const float* __restrict__ q,
                                              const float* __restrict__ dinv,
                                              const float* __restrict__ b2,
                                              float* __restrict__ out, int n) {
    __shared__ float acc[128];
    int b = blockIdx.x, tid = threadIdx.x;
    if (tid < 128) acc[tid] = 0.f;
    __syncthreads();
    int j1 = bstart[b + 1];
    for (int j = bstart[b] + tid; j < j1; j += 256) {
        int key = skey[j];
        atomicAdd(&acc[key >> 17], sw[j] * q[key & 0x1FFFF]);
    }
    __syncthreads();
    int node = (b << BSH) + tid;
    if (tid < 128 && node < n)
        out[node] = b2[0] + dinv[node] * (q[node] + acc[tid]);
}

extern "C" void kernel_launch(void* const* d_in, const int* in_sizes, int n_in,
                              void* d_out, int out_size, void* d_ws, size_t ws_size,
                              hipStream_t stream) {
    const float* x   = (const float*)d_in[0];
    const int*   ei  = (const int*)d_in[1];
    const float* w   = (const float*)d_in[2];
    const float* W1  = (const float*)d_in[3];
    const float* b1  = (const float*)d_in[4];
    const float* W2  = (const float*)d_in[5];
    const float* b2  = (const float*)d_in[6];
    float* out = (float*)d_out;

    const int n     = in_sizes[0] / CH;    // 100000
    const int e_cnt = in_sizes[2];         // 1600000
    const int* row = ei;
    const int* col = ei + e_cnt;

    const int nbuck  = (n + 127) >> BSH;               // 782
    const int nchunk = (e_cnt + CHUNK - 1) / CHUNK;    // 782

    // ---- workspace layout ----
    float* u      = (float*)d_ws;                       // 132
    float* t      = u + 132;                            // n
    float* dinv   = t + n;                              // n
    float* p      = dinv + n;                           // n
    float* q      = p + n;                              // n
    int*   coltot = (int*)(q + n);                      // nbuck
    int*   bstart = coltot + nbuck;                     // nbuck+1
    int*   Ht     = bstart + nbuck + 1;                 // nchunk*nbuck
    int*   skey   = Ht + (size_t)nchunk * nbuck;        // e_cnt
    float* sw     = (float*)(skey + e_cnt);             // e_cnt

    k_uw<<<(CH + 1 + 3) / 4, 256, 0, stream>>>(W1, b1, W2, u);
    k_gemv<<<(n + 7) / 8, 256, 0, stream>>>(x, u, t, n);

    k_hist<<<nchunk, 256, 0, stream>>>(col, Ht, nbuck, e_cnt);
    k_colscan<<<(nbuck + 3) / 4, 256, 0, stream>>>(Ht, coltot, nchunk, nbuck);
    k_basescan<<<1, 64, 0, stream>>>(coltot, bstart, nbuck);
    k_permute<<<nchunk, 256, 0, stream>>>(row, col, w, Ht, bstart, skey, sw, nbuck, e_cnt);

    k_dega<<<nbuck, 256, 0, stream>>>(skey, sw, bstart, t, dinv, p, n);
    k_s1a<<<nbuck, 256, 0, stream>>>(skey, sw, bstart, p, dinv, u, q, n);
    k_outa<<<nbuck, 256, 0, stream>>>(skey, sw, bstart, q, dinv, b2, out, n);
}